// Round 6
// baseline (437.235 us; speedup 1.0000x reference)
//
#include <hip/hip_runtime.h>
#include <hip/hip_bf16.h>
#include <cstdint>
#include <cstddef>

#define N_ACT 200000
#define CH 128
#define NOFF 27
#define TM 128

typedef __bf16 v8bf __attribute__((ext_vector_type(8)));
typedef float v4f __attribute__((ext_vector_type(4)));

__device__ __forceinline__ unsigned short f2bf(float f) {
    union { float f; unsigned int u; } x; x.f = f;
    unsigned int lsb = (x.u >> 16) & 1u;
    x.u += 0x7fffu + lsb;            // round-to-nearest-even
    return (unsigned short)(x.u >> 16);
}

// async global->LDS, 16 B per lane (global_load_lds_dwordx4).
// LDS dest is WAVE-UNIFORM base + lane*16; global src is per-lane.
__device__ __forceinline__ void gload_lds16(const void* g, void* l) {
    __builtin_amdgcn_global_load_lds(
        (const __attribute__((address_space(1))) unsigned int*)g,
        (__attribute__((address_space(3))) unsigned int*)l,
        16, 0, 0);
}

// K1a: cast features fp32 -> bf16, 8 elements/thread
__global__ void cast_feat(const float* __restrict__ in,
                          unsigned short* __restrict__ out) {
    long long i = (long long)blockIdx.x * blockDim.x + threadIdx.x;
    long long base = i * 8;
    if (base >= (long long)N_ACT * CH) return;
    const float4* p = (const float4*)(in + base);
    float4 a = p[0], b = p[1];
    unsigned int w0 = (unsigned)f2bf(a.x) | ((unsigned)f2bf(a.y) << 16);
    unsigned int w1 = (unsigned)f2bf(a.z) | ((unsigned)f2bf(a.w) << 16);
    unsigned int w2 = (unsigned)f2bf(b.x) | ((unsigned)f2bf(b.y) << 16);
    unsigned int w3 = (unsigned)f2bf(b.z) | ((unsigned)f2bf(b.w) << 16);
    *(uint4*)(out + base) = make_uint4(w0, w1, w2, w3);
}

// K1b: pack W[k][cin][cout] fp32 into fragment-order bf16:
//   Wtp[(k*4+q)*4096 + (jkk*64 + lane)*8 + e]
// q = col-quarter (wave id), jkk = j*4+kk, lane = quad*16+lr,
// value = W[k][kk*32+quad*8+e][q*32+j*16+lr].
__global__ void prep_w(const float* __restrict__ W,
                       unsigned short* __restrict__ Wtp,
                       float* __restrict__ stats,
                       float* __restrict__ zpage) {
    int k = blockIdx.x;
    int t = threadIdx.x;
    if (k == 0 && t < 2 * CH) stats[t] = 0.0f;   // sums + sumsq
    if (k == 0 && t < 64) zpage[t] = 0.0f;       // 256 B zero row for gathers
    const float* wk = W + (size_t)k * CH * CH;
    for (int g = t; g < 2048; g += 256) {
        int q = g >> 9, r = g & 511;
        int jkk = r >> 6, lane = r & 63;
        int j = jkk >> 2, kk = jkk & 3;
        int lr = lane & 15, quad = lane >> 4;
        int cout = q * 32 + j * 16 + lr;
        int cin0 = kk * 32 + quad * 8;
        unsigned int wbuf[4];
        #pragma unroll
        for (int h = 0; h < 4; ++h) {
            unsigned short lo = f2bf(wk[(size_t)(cin0 + 2*h)     * CH + cout]);
            unsigned short hi = f2bf(wk[(size_t)(cin0 + 2*h + 1) * CH + cout]);
            wbuf[h] = (unsigned)lo | ((unsigned)hi << 16);
        }
        *(uint4*)(Wtp + ((size_t)(k * 4 + q) << 12) + (size_t)(jkk * 64 + lane) * 8)
            = make_uint4(wbuf[0], wbuf[1], wbuf[2], wbuf[3]);
    }
}

// K2: m97-style pipeline. Per k: ISSUE gathers for k+1 via global_load_lds
// into As[cur^1] (zero VGPR cost, DMA direct to LDS) | mfmaPhase on As[cur]
// (~1200cy, covers the gather latency) | loadB(k+1) | ONE barrier (drains
// vmcnt -> As[cur^1]+B complete) | swap. The stage phase is off the
// critical path; R4's spill mode is impossible (no G registers).
// Swizzle preserved by INVERSE-swizzling the per-lane global source:
// dest chunk c of row r fetches global chunk (c-r)&15, so the unchanged
// MFMA-phase read (pos (kk*4+quad+lr)&15 at row i*16+lr) sees chunk
// (kk*4+quad)&15 as before.
__global__ __launch_bounds__(256, 2) void conv_mfma(
        const unsigned short* __restrict__ feat,   // [N][128] bf16
        const int* __restrict__ nbr,               // [27][N]
        const unsigned short* __restrict__ Wtp,    // packed (see prep_w)
        const unsigned short* __restrict__ zpage,  // 256 B of zeros
        float* __restrict__ out,                   // [N][128] conv result
        float* __restrict__ stats) {               // sums[128], sumsq[128]
    __shared__ __bf16 As[2 * TM * CH];             // 2 x 32 KB double buffer
    __shared__ int idxL[NOFF * TM];                // 13.8 KB
    __shared__ float sred[256];                    // 1 KB

    const int t    = threadIdx.x;
    const int row0 = blockIdx.x * TM;
    const int wid  = t >> 6;
    const int lane = t & 63;
    const int lr   = lane & 15;
    const int quad = lane >> 4;
    const int sc   = lane & 15;     // dest chunk this lane stages
    const int lhi  = lane >> 4;     // row-within-wave-group
    const int wv4  = wid * 4;       // wave's 4-row group base

    // ---- stage the whole neighbor-index table once (coalesced)
    for (int e = t; e < NOFF * TM; e += 256) {
        int k = e >> 7, r = e & 127;
        int gr = row0 + r;
        idxL[e] = (gr < N_ACT) ? nbr[(size_t)k * N_ACT + gr] : -1;
    }
    __syncthreads();

    v4f acc[8][2];
    #pragma unroll
    for (int i = 0; i < 8; ++i) {
        acc[i][0] = (v4f){0.f, 0.f, 0.f, 0.f};
        acc[i][1] = (v4f){0.f, 0.f, 0.f, 0.f};
    }

    v8bf B[8];           // B fragment set for current k

    // issue 8 direct-to-LDS gathers for offset k into buffer buf.
    // lane writes dest (row p*16+wv4+lhi, chunk sc) = base + lane*16B;
    // source pre-swizzled: global chunk (sc - row) & 15.
    auto issueStage = [&](int k, int buf) {
        __bf16* dstbase = As + buf * (TM * CH);
        #pragma unroll
        for (int p = 0; p < 8; ++p) {
            int row = p * 16 + wv4 + lhi;
            int idx = idxL[k * TM + row];
            int gch = (sc - row) & 15;
            const unsigned short* src = (idx >= 0)
                ? feat + ((size_t)idx << 7) + gch * 8
                : zpage + gch * 8;
            gload_lds16(src, dstbase + (size_t)(p * 16 + wv4) * CH);
        }
    };
    auto loadB = [&](int k) {
        const unsigned short* base =
            Wtp + ((size_t)(k * 4 + wid) << 12) + (size_t)lane * 8;
        #pragma unroll
        for (int jkk = 0; jkk < 8; ++jkk)
            B[jkk] = *(const v8bf*)(base + jkk * 512);
    };
    // i-blocked: per row-subtile load 4 a-frags (16 regs), fire 8 MFMAs
    auto mfmaPhase = [&](const __bf16* buf) {
        #pragma unroll
        for (int i = 0; i < 8; ++i) {
            const __bf16* rowp = buf + (i * 16 + lr) * CH;
            v8bf a[4];
            #pragma unroll
            for (int kk = 0; kk < 4; ++kk)
                a[kk] = *(const v8bf*)(rowp + (((kk * 4 + quad + lr) & 15) << 3));
            #pragma unroll
            for (int kk = 0; kk < 4; ++kk) {
                acc[i][0] = __builtin_amdgcn_mfma_f32_16x16x32_bf16(
                    a[kk], B[kk], acc[i][0], 0, 0, 0);
                acc[i][1] = __builtin_amdgcn_mfma_f32_16x16x32_bf16(
                    a[kk], B[4 + kk], acc[i][1], 0, 0, 0);
            }
        }
    };

    // ---- prologue: stage k=0 into buffer 0
    issueStage(0, 0);
    loadB(0);
    __syncthreads();     // drains vmcnt(0): buffer 0 + B complete

    // ---- k-loop: ONE barrier per k. Safety: issueStage(k+1) writes
    // As[cur^1], which was last READ in iter k-1; the iter k-1 barrier
    // ordered those reads before any wave issues these writes.
    int cur = 0;
    #pragma unroll 1
    for (int k = 0; k < NOFF; ++k) {
        if (k + 1 < NOFF) issueStage(k + 1, cur ^ 1);  // DMA in flight
        mfmaPhase(As + cur * (TM * CH));
        if (k + 1 < NOFF) {
            loadB(k + 1);          // B consumed; refill for next k
            __syncthreads();       // vmcnt(0): stage + B landed
            cur ^= 1;
        }
    }

    // ---- epilogue: store conv result + per-column partial stats
    float psum[2] = {0.f, 0.f};
    float psq[2]  = {0.f, 0.f};
    #pragma unroll
    for (int i = 0; i < 8; ++i) {
        #pragma unroll
        for (int r = 0; r < 4; ++r) {
            int grow = row0 + i * 16 + quad * 4 + r;
            if (grow < N_ACT) {
                #pragma unroll
                for (int j = 0; j < 2; ++j) {
                    float v = acc[i][j][r];
                    out[(size_t)grow * CH + wid * 32 + j * 16 + lr] = v;
                    psum[j] += v;
                    psq[j]  += v * v;
                }
            }
        }
    }
    #pragma unroll
    for (int j = 0; j < 2; ++j) {
        psum[j] += __shfl_xor(psum[j], 16, 64);
        psq[j]  += __shfl_xor(psq[j], 16, 64);
        psum[j] += __shfl_xor(psum[j], 32, 64);
        psq[j]  += __shfl_xor(psq[j], 32, 64);
    }
    if (quad == 0) {
        #pragma unroll
        for (int j = 0; j < 2; ++j) {
            int c = wid * 32 + j * 16 + lr;
            sred[c]       = psum[j];
            sred[128 + c] = psq[j];
        }
    }
    __syncthreads();
    if (t < CH) {
        atomicAdd(&stats[t],      sred[t]);
        atomicAdd(&stats[CH + t], sred[128 + t]);
    }
}

// K3: per-channel scale/shift from batch stats
__global__ void finalize_stats(const float* __restrict__ gamma,
                               const float* __restrict__ beta,
                               float* __restrict__ stats) {
    int c = threadIdx.x;
    if (c < CH) {
        float inv_n = 1.0f / (float)N_ACT;
        float mean  = stats[c] * inv_n;
        float var   = stats[CH + c] * inv_n - mean * mean;
        float sc    = gamma[c] * rsqrtf(var + 1e-4f);
        stats[2 * CH + c] = sc;
        stats[3 * CH + c] = beta[c] - mean * sc;
    }
}

// K4: out = relu(conv * scale[c] + shift[c]), float4
__global__ void bn_relu(const float* __restrict__ conv,
                        const float* __restrict__ stats,
                        float* __restrict__ out) {
    long long i = (long long)blockIdx.x * blockDim.x + threadIdx.x;
    if (i >= (long long)N_ACT * CH / 4) return;
    int c4 = (int)(i & 31) * 4;
    float4 v  = ((const float4*)conv)[i];
    float4 sc = *(const float4*)(stats + 2 * CH + c4);
    float4 sh = *(const float4*)(stats + 3 * CH + c4);
    float4 o;
    o.x = fmaxf(v.x * sc.x + sh.x, 0.f);
    o.y = fmaxf(v.y * sc.y + sh.y, 0.f);
    o.z = fmaxf(v.z * sc.z + sh.z, 0.f);
    o.w = fmaxf(v.w * sc.w + sh.w, 0.f);
    ((float4*)out)[i] = o;
}

extern "C" void kernel_launch(void* const* d_in, const int* in_sizes, int n_in,
                              void* d_out, int out_size, void* d_ws, size_t ws_size,
                              hipStream_t stream) {
    const float* features = (const float*)d_in[0];
    const int*   nbr      = (const int*)d_in[1];
    const float* W        = (const float*)d_in[2];
    const float* gamma    = (const float*)d_in[3];
    const float* beta     = (const float*)d_in[4];
    float* outp = (float*)d_out;

    char* ws = (char*)d_ws;
    // layout: feat_bf16 (51,200,000 B) | Wtp (884,736 B) | conv fp32
    // (102,400,000 B) | stats (512 floats) | zero page (256 B)
    unsigned short* feat_bf = (unsigned short*)ws;
    unsigned short* Wtp     = (unsigned short*)(ws + 51200000);
    float* conv             = (float*)(ws + 51200000 + 884736);
    float* stats            = (float*)(ws + 51200000 + 884736 + 102400000);
    float* zpage            = stats + 4 * CH;

    cast_feat<<<12500, 256, 0, stream>>>(features, feat_bf);
    prep_w<<<NOFF, 256, 0, stream>>>(W, Wtp, stats, zpage);
    conv_mfma<<<(N_ACT + TM - 1) / TM, 256, 0, stream>>>(
        feat_bf, nbr, Wtp, (const unsigned short*)zpage, conv, stats);
    finalize_stats<<<1, CH, 0, stream>>>(gamma, beta, stats);
    bn_relu<<<25000, 256, 0, stream>>>(conv, stats, outp);
}

// Round 7
// 410.840 us; speedup vs baseline: 1.0642x; 1.0642x over previous
//
#include <hip/hip_runtime.h>
#include <hip/hip_bf16.h>
#include <cstdint>
#include <cstddef>

#define N_ACT 200000
#define CH 128
#define NOFF 27
#define TM 64      // 64-row tile: dbuf LDS 39.7 KB -> 4 blocks/CU, AND
                   // async gload_lds pipeline (R6) -> stage off critical path

typedef __bf16 v8bf __attribute__((ext_vector_type(8)));
typedef float v4f __attribute__((ext_vector_type(4)));

__device__ __forceinline__ unsigned short f2bf(float f) {
    union { float f; unsigned int u; } x; x.f = f;
    unsigned int lsb = (x.u >> 16) & 1u;
    x.u += 0x7fffu + lsb;            // round-to-nearest-even
    return (unsigned short)(x.u >> 16);
}

// async global->LDS, 16 B per lane (global_load_lds_dwordx4).
// LDS dest is WAVE-UNIFORM base + lane*16; global src is per-lane.
__device__ __forceinline__ void gload_lds16(const void* g, void* l) {
    __builtin_amdgcn_global_load_lds(
        (const __attribute__((address_space(1))) unsigned int*)g,
        (__attribute__((address_space(3))) unsigned int*)l,
        16, 0, 0);
}

// K1a: cast features fp32 -> bf16, 8 elements/thread
__global__ void cast_feat(const float* __restrict__ in,
                          unsigned short* __restrict__ out) {
    long long i = (long long)blockIdx.x * blockDim.x + threadIdx.x;
    long long base = i * 8;
    if (base >= (long long)N_ACT * CH) return;
    const float4* p = (const float4*)(in + base);
    float4 a = p[0], b = p[1];
    unsigned int w0 = (unsigned)f2bf(a.x) | ((unsigned)f2bf(a.y) << 16);
    unsigned int w1 = (unsigned)f2bf(a.z) | ((unsigned)f2bf(a.w) << 16);
    unsigned int w2 = (unsigned)f2bf(b.x) | ((unsigned)f2bf(b.y) << 16);
    unsigned int w3 = (unsigned)f2bf(b.z) | ((unsigned)f2bf(b.w) << 16);
    *(uint4*)(out + base) = make_uint4(w0, w1, w2, w3);
}

// K1b: pack W[k][cin][cout] fp32 into fragment-order bf16:
//   Wtp[(k*4+q)*4096 + (jkk*64 + lane)*8 + e]
// q = col-quarter (wave id), jkk = j*4+kk, lane = quad*16+lr,
// value = W[k][kk*32+quad*8+e][q*32+j*16+lr].
__global__ void prep_w(const float* __restrict__ W,
                       unsigned short* __restrict__ Wtp,
                       float* __restrict__ stats,
                       float* __restrict__ zpage) {
    int k = blockIdx.x;
    int t = threadIdx.x;
    if (k == 0 && t < 2 * CH) stats[t] = 0.0f;   // sums + sumsq
    if (k == 0 && t < 64) zpage[t] = 0.0f;       // 256 B zero row for gathers
    const float* wk = W + (size_t)k * CH * CH;
    for (int g = t; g < 2048; g += 256) {
        int q = g >> 9, r = g & 511;
        int jkk = r >> 6, lane = r & 63;
        int j = jkk >> 2, kk = jkk & 3;
        int lr = lane & 15, quad = lane >> 4;
        int cout = q * 32 + j * 16 + lr;
        int cin0 = kk * 32 + quad * 8;
        unsigned int wbuf[4];
        #pragma unroll
        for (int h = 0; h < 4; ++h) {
            unsigned short lo = f2bf(wk[(size_t)(cin0 + 2*h)     * CH + cout]);
            unsigned short hi = f2bf(wk[(size_t)(cin0 + 2*h + 1) * CH + cout]);
            wbuf[h] = (unsigned)lo | ((unsigned)hi << 16);
        }
        *(uint4*)(Wtp + ((size_t)(k * 4 + q) << 12) + (size_t)(jkk * 64 + lane) * 8)
            = make_uint4(wbuf[0], wbuf[1], wbuf[2], wbuf[3]);
    }
}

// K2: TM=64 double-buffered async pipeline at 4 blocks/CU.
// Per k: ISSUE 4 DMA gathers for k+1 into As[cur^1] (zero VGPR) |
// mfmaPhase on As[cur] (32 MFMA/wave covers gather latency; 4 waves/SIMD
// from 4 co-resident blocks stack to ~600cy MFMA per SIMD per k) |
// loadB(k+1) | ONE barrier (vmcnt drain: DMA + B landed) | swap.
// Swizzle preserved by inverse-swizzling the per-lane global source
// (proven correct in R6): dest chunk sc of row r fetches global chunk
// (sc-r)&15; MFMA read (pos (kk*4+quad+lr)&15 @ row i*16+lr) unchanged.
__global__ __launch_bounds__(256, 4) void conv_mfma(
        const unsigned short* __restrict__ feat,   // [N][128] bf16
        const int* __restrict__ nbr,               // [27][N]
        const unsigned short* __restrict__ Wtp,    // packed (see prep_w)
        const unsigned short* __restrict__ zpage,  // 256 B of zeros
        float* __restrict__ out,                   // [N][128] conv result
        float* __restrict__ stats) {               // sums[128], sumsq[128]
    __shared__ __bf16 As[2 * TM * CH];             // 2 x 16 KB double buffer
    __shared__ int idxL[NOFF * TM];                // 6.75 KB

    const int t    = threadIdx.x;
    const int row0 = blockIdx.x * TM;              // 3125*64 == N_ACT exactly
    const int wid  = t >> 6;
    const int lane = t & 63;
    const int lr   = lane & 15;
    const int quad = lane >> 4;
    const int sc   = lane & 15;     // dest chunk this lane stages
    const int lhi  = lane >> 4;     // row-within-wave-group
    const int wv4  = wid * 4;       // wave's 4-row group base

    // ---- stage the whole neighbor-index table once (coalesced)
    for (int e = t; e < NOFF * TM; e += 256) {
        int k = e >> 6, r = e & 63;
        idxL[e] = nbr[(size_t)k * N_ACT + row0 + r];
    }
    __syncthreads();

    v4f acc[4][2];
    #pragma unroll
    for (int i = 0; i < 4; ++i) {
        acc[i][0] = (v4f){0.f, 0.f, 0.f, 0.f};
        acc[i][1] = (v4f){0.f, 0.f, 0.f, 0.f};
    }

    v8bf B[8];           // B fragment set for current k

    // issue 4 direct-to-LDS gathers for offset k into buffer buf.
    // wave w stages rows {p*16 + w*4 + 0..3}, lane covers (row lhi, chunk sc)
    auto issueStage = [&](int k, int buf) {
        __bf16* dstbase = As + buf * (TM * CH);
        #pragma unroll
        for (int p = 0; p < 4; ++p) {
            int row = p * 16 + wv4 + lhi;
            int idx = idxL[k * TM + row];
            int gch = (sc - row) & 15;
            const unsigned short* src = (idx >= 0)
                ? feat + ((size_t)idx << 7) + gch * 8
                : zpage + gch * 8;
            gload_lds16(src, dstbase + (size_t)(p * 16 + wv4) * CH);
        }
    };
    auto loadB = [&](int k) {
        const unsigned short* base =
            Wtp + ((size_t)(k * 4 + wid) << 12) + (size_t)lane * 8;
        #pragma unroll
        for (int jkk = 0; jkk < 8; ++jkk)
            B[jkk] = *(const v8bf*)(base + jkk * 512);
    };
    // i-blocked: per row-subtile load 4 a-frags (16 regs), fire 8 MFMAs
    auto mfmaPhase = [&](const __bf16* buf) {
        #pragma unroll
        for (int i = 0; i < 4; ++i) {
            const __bf16* rowp = buf + (i * 16 + lr) * CH;
            v8bf a[4];
            #pragma unroll
            for (int kk = 0; kk < 4; ++kk)
                a[kk] = *(const v8bf*)(rowp + (((kk * 4 + quad + lr) & 15) << 3));
            #pragma unroll
            for (int kk = 0; kk < 4; ++kk) {
                acc[i][0] = __builtin_amdgcn_mfma_f32_16x16x32_bf16(
                    a[kk], B[kk], acc[i][0], 0, 0, 0);
                acc[i][1] = __builtin_amdgcn_mfma_f32_16x16x32_bf16(
                    a[kk], B[4 + kk], acc[i][1], 0, 0, 0);
            }
        }
    };

    // ---- prologue: stage k=0 into buffer 0
    issueStage(0, 0);
    loadB(0);
    __syncthreads();     // vmcnt(0) drain: buffer 0 + B complete

    // ---- k-loop: ONE barrier per k. Write-after-read safe: As[cur^1] was
    // last read in iter k-1, whose barrier (lgkmcnt(0) per wave) ordered
    // all reads before any wave issues these DMA writes.
    int cur = 0;
    #pragma unroll 1
    for (int k = 0; k < NOFF; ++k) {
        if (k + 1 < NOFF) issueStage(k + 1, cur ^ 1);  // DMA in flight
        mfmaPhase(As + cur * (TM * CH));
        if (k + 1 < NOFF) {
            loadB(k + 1);          // B consumed; refill for next k
            __syncthreads();       // vmcnt(0): stage + B landed
            cur ^= 1;
        }
    }

    // ---- epilogue: store conv result + stats (direct atomics, no LDS)
    float psum[2] = {0.f, 0.f};
    float psq[2]  = {0.f, 0.f};
    #pragma unroll
    for (int i = 0; i < 4; ++i) {
        #pragma unroll
        for (int r = 0; r < 4; ++r) {
            int grow = row0 + i * 16 + quad * 4 + r;
            #pragma unroll
            for (int j = 0; j < 2; ++j) {
                float v = acc[i][j][r];
                out[(size_t)grow * CH + wid * 32 + j * 16 + lr] = v;
                psum[j] += v;
                psq[j]  += v * v;
            }
        }
    }
    #pragma unroll
    for (int j = 0; j < 2; ++j) {
        psum[j] += __shfl_xor(psum[j], 16, 64);
        psq[j]  += __shfl_xor(psq[j], 16, 64);
        psum[j] += __shfl_xor(psum[j], 32, 64);
        psq[j]  += __shfl_xor(psq[j], 32, 64);
    }
    if (quad == 0) {
        #pragma unroll
        for (int j = 0; j < 2; ++j) {
            int c = wid * 32 + j * 16 + lr;
            atomicAdd(&stats[c],      psum[j]);
            atomicAdd(&stats[CH + c], psq[j]);
        }
    }
}

// K3: per-channel scale/shift from batch stats
__global__ void finalize_stats(const float* __restrict__ gamma,
                               const float* __restrict__ beta,
                               float* __restrict__ stats) {
    int c = threadIdx.x;
    if (c < CH) {
        float inv_n = 1.0f / (float)N_ACT;
        float mean  = stats[c] * inv_n;
        float var   = stats[CH + c] * inv_n - mean * mean;
        float sc    = gamma[c] * rsqrtf(var + 1e-4f);
        stats[2 * CH + c] = sc;
        stats[3 * CH + c] = beta[c] - mean * sc;
    }
}

// K4: out = relu(conv * scale[c] + shift[c]), float4
__global__ void bn_relu(const float* __restrict__ conv,
                        const float* __restrict__ stats,
                        float* __restrict__ out) {
    long long i = (long long)blockIdx.x * blockDim.x + threadIdx.x;
    if (i >= (long long)N_ACT * CH / 4) return;
    int c4 = (int)(i & 31) * 4;
    float4 v  = ((const float4*)conv)[i];
    float4 sc = *(const float4*)(stats + 2 * CH + c4);
    float4 sh = *(const float4*)(stats + 3 * CH + c4);
    float4 o;
    o.x = fmaxf(v.x * sc.x + sh.x, 0.f);
    o.y = fmaxf(v.y * sc.y + sh.y, 0.f);
    o.z = fmaxf(v.z * sc.z + sh.z, 0.f);
    o.w = fmaxf(v.w * sc.w + sh.w, 0.f);
    ((float4*)out)[i] = o;
}

extern "C" void kernel_launch(void* const* d_in, const int* in_sizes, int n_in,
                              void* d_out, int out_size, void* d_ws, size_t ws_size,
                              hipStream_t stream) {
    const float* features = (const float*)d_in[0];
    const int*   nbr      = (const int*)d_in[1];
    const float* W        = (const float*)d_in[2];
    const float* gamma    = (const float*)d_in[3];
    const float* beta     = (const float*)d_in[4];
    float* outp = (float*)d_out;

    char* ws = (char*)d_ws;
    // layout: feat_bf16 (51,200,000 B) | Wtp (884,736 B) | conv fp32
    // (102,400,000 B) | stats (512 floats) | zero page (256 B)
    unsigned short* feat_bf = (unsigned short*)ws;
    unsigned short* Wtp     = (unsigned short*)(ws + 51200000);
    float* conv             = (float*)(ws + 51200000 + 884736);
    float* stats            = (float*)(ws + 51200000 + 884736 + 102400000);
    float* zpage            = stats + 4 * CH;

    cast_feat<<<12500, 256, 0, stream>>>(features, feat_bf);
    prep_w<<<NOFF, 256, 0, stream>>>(W, Wtp, stats, zpage);
    conv_mfma<<<N_ACT / TM, 256, 0, stream>>>(
        feat_bf, nbr, Wtp, (const unsigned short*)zpage, conv, stats);
    finalize_stats<<<1, CH, 0, stream>>>(gamma, beta, stats);
    bn_relu<<<25000, 256, 0, stream>>>(conv, stats, outp);
}

// Round 9
// 385.165 us; speedup vs baseline: 1.1352x; 1.0667x over previous
//
#include <hip/hip_runtime.h>
#include <hip/hip_bf16.h>
#include <cstdint>
#include <cstddef>

#define N_ACT 200000
#define CH 128
#define NOFF 27
#define TM 128

typedef __bf16 v8bf __attribute__((ext_vector_type(8)));
typedef float v4f __attribute__((ext_vector_type(4)));

__device__ __forceinline__ unsigned short f2bf(float f) {
    union { float f; unsigned int u; } x; x.f = f;
    unsigned int lsb = (x.u >> 16) & 1u;
    x.u += 0x7fffu + lsb;            // round-to-nearest-even
    return (unsigned short)(x.u >> 16);
}

// async global->LDS. LDS dest is WAVE-UNIFORM base + lane*size.
__device__ __forceinline__ void gload_lds16(const void* g, void* l) {
    __builtin_amdgcn_global_load_lds(
        (const __attribute__((address_space(1))) unsigned int*)g,
        (__attribute__((address_space(3))) unsigned int*)l,
        16, 0, 0);
}
__device__ __forceinline__ void gload_lds4(const void* g, void* l) {
    __builtin_amdgcn_global_load_lds(
        (const __attribute__((address_space(1))) unsigned int*)g,
        (__attribute__((address_space(3))) unsigned int*)l,
        4, 0, 0);
}

// K1: fused prep_w (blocks 0..26) + cast_feat (grid-stride, remaining blocks)
__global__ void prep_and_cast(const float* __restrict__ features,
                              const float* __restrict__ W,
                              unsigned short* __restrict__ feat_bf,
                              unsigned short* __restrict__ Wtp,
                              float* __restrict__ stats,
                              float* __restrict__ zpage) {
    int t = threadIdx.x;
    if (blockIdx.x < NOFF) {
        // ---- prep_w: pack W[k][cin][cout] fp32 into fragment-order bf16:
        //   Wtp[(k*4+q)*4096 + (jkk*64 + lane)*8 + e]
        // value = W[k][kk*32+quad*8+e][q*32+j*16+lr].
        int k = blockIdx.x;
        if (k == 0 && t < 2 * CH) stats[t] = 0.0f;   // sums + sumsq
        if (k == 0 && t < 64) zpage[t] = 0.0f;       // zero row for gathers
        const float* wk = W + (size_t)k * CH * CH;
        for (int g = t; g < 2048; g += 256) {
            int q = g >> 9, r = g & 511;
            int jkk = r >> 6, lane = r & 63;
            int j = jkk >> 2, kk = jkk & 3;
            int lr = lane & 15, quad = lane >> 4;
            int cout = q * 32 + j * 16 + lr;
            int cin0 = kk * 32 + quad * 8;
            unsigned int wbuf[4];
            #pragma unroll
            for (int h = 0; h < 4; ++h) {
                unsigned short lo = f2bf(wk[(size_t)(cin0 + 2*h)     * CH + cout]);
                unsigned short hi = f2bf(wk[(size_t)(cin0 + 2*h + 1) * CH + cout]);
                wbuf[h] = (unsigned)lo | ((unsigned)hi << 16);
            }
            *(uint4*)(Wtp + ((size_t)(k * 4 + q) << 12)
                          + (size_t)(jkk * 64 + lane) * 8)
                = make_uint4(wbuf[0], wbuf[1], wbuf[2], wbuf[3]);
        }
        return;
    }
    // ---- cast_feat: fp32 -> bf16, 8 elems/thread/iter, grid-stride
    const long long total = (long long)N_ACT * CH / 8;   // 3.2M groups
    long long stride = (long long)(gridDim.x - NOFF) * blockDim.x;
    for (long long i = (long long)(blockIdx.x - NOFF) * blockDim.x + t;
         i < total; i += stride) {
        long long base = i * 8;
        const float4* p = (const float4*)(features + base);
        float4 a = p[0], b = p[1];
        unsigned int w0 = (unsigned)f2bf(a.x) | ((unsigned)f2bf(a.y) << 16);
        unsigned int w1 = (unsigned)f2bf(a.z) | ((unsigned)f2bf(a.w) << 16);
        unsigned int w2 = (unsigned)f2bf(b.x) | ((unsigned)f2bf(b.y) << 16);
        unsigned int w3 = (unsigned)f2bf(b.z) | ((unsigned)f2bf(b.w) << 16);
        *(uint4*)(feat_bf + base) = make_uint4(w0, w1, w2, w3);
    }
}

// K2: TM=128 serial 2-barrier loop, gload_lds staging (zero VGPR), 1 KB
// 2-slot idx dbuf DMA'd one k ahead (replaces 13.8 KB idxL). LDS 33 KB ->
// 4 blocks/CU; unified regs 64 AGPR + ~60 VGPR <= 128 -> 4 waves/SIMD.
// B traffic: 1563 blocks x 864 KB = 1.35 GB (half of R7's TM=64).
// Per k: MFMA(k) | barrier | DMA stage(k+1) + DMA idx(k+2) + loadB(k+1)
// | barrier (vmcnt drain). Cross-block TLP (4 blocks) covers the stage.
__global__ __launch_bounds__(256, 4) void conv_mfma(
        const unsigned short* __restrict__ feat,   // [N][128] bf16
        const int* __restrict__ nbr,               // [27][N]
        const unsigned short* __restrict__ Wtp,    // packed (see prep)
        const unsigned short* __restrict__ zpage,  // 256 B of zeros
        float* __restrict__ out,                   // [N][128] conv result
        float* __restrict__ stats) {               // sums[128], sumsq[128]
    __shared__ __bf16 As[TM * CH];                 // 32 KB, rotated chunks
    __shared__ int idxS[2][TM];                    // 1 KB, idx double-buffer

    const int t    = threadIdx.x;
    const int row0 = blockIdx.x * TM;
    const int wid  = t >> 6;
    const int lane = t & 63;
    const int lr   = lane & 15;
    const int quad = lane >> 4;
    const int sc   = lane & 15;     // dest chunk this lane stages
    const int lhi  = lane >> 4;     // row-within-wave-group
    const int wv4  = wid * 4;       // wave's 4-row group base

    v4f acc[8][2];
    #pragma unroll
    for (int i = 0; i < 8; ++i) {
        acc[i][0] = (v4f){0.f, 0.f, 0.f, 0.f};
        acc[i][1] = (v4f){0.f, 0.f, 0.f, 0.f};
    }

    v8bf B[8];           // B fragment set for current k

    // DMA the 128 neighbor indices of offset k into idxS[slot] (wave 0
    // only; 2x size-4 gload). Tail rows clamped to a valid row: the
    // gathered garbage rows are masked in the epilogue (grow < N_ACT).
    auto idxDMA = [&](int k, int slot) {
        const int* src = nbr + (size_t)k * N_ACT;
        int r0 = min(row0 + lane,      N_ACT - 1);
        int r1 = min(row0 + 64 + lane, N_ACT - 1);
        gload_lds4(src + r0, &idxS[slot][0]);
        gload_lds4(src + r1, &idxS[slot][64]);
    };
    // issue 8 direct-to-LDS gathers into As. Dest: row p*16+wv4+lhi,
    // chunk sc (= uniform base + lane*16). Source inverse-rotated:
    // global chunk (sc - row) & 15, so the MFMA read (chunk
    // (kk*4+quad+lr)&15 at row i*16+lr) sees stored chunk (kk*4+quad)&15.
    auto stageA = [&](int slot) {
        #pragma unroll
        for (int p = 0; p < 8; ++p) {
            int row = p * 16 + wv4 + lhi;
            int idx = idxS[slot][row];
            int gch = (sc - row) & 15;
            const unsigned short* src = (idx >= 0)
                ? feat + ((size_t)idx << 7) + gch * 8
                : zpage + gch * 8;
            gload_lds16(src, As + (size_t)(p * 16 + wv4) * CH);
        }
    };
    auto loadB = [&](int k) {
        const unsigned short* base =
            Wtp + ((size_t)(k * 4 + wid) << 12) + (size_t)lane * 8;
        #pragma unroll
        for (int jkk = 0; jkk < 8; ++jkk)
            B[jkk] = *(const v8bf*)(base + jkk * 512);
    };
    // i-blocked: per row-subtile load 4 a-frags (16 regs), fire 8 MFMAs
    auto mfmaPhase = [&]() {
        #pragma unroll
        for (int i = 0; i < 8; ++i) {
            const __bf16* rowp = As + (i * 16 + lr) * CH;
            v8bf a[4];
            #pragma unroll
            for (int kk = 0; kk < 4; ++kk)
                a[kk] = *(const v8bf*)(rowp + (((kk * 4 + quad + lr) & 15) << 3));
            #pragma unroll
            for (int kk = 0; kk < 4; ++kk) {
                acc[i][0] = __builtin_amdgcn_mfma_f32_16x16x32_bf16(
                    a[kk], B[kk], acc[i][0], 0, 0, 0);
                acc[i][1] = __builtin_amdgcn_mfma_f32_16x16x32_bf16(
                    a[kk], B[4 + kk], acc[i][1], 0, 0, 0);
            }
        }
    };

    // ---- prologue
    if (wid == 0) idxDMA(0, 0);
    __syncthreads();               // idx[0] landed (wave0 vmcnt drained)
    stageA(0);
    if (wid == 0) idxDMA(1, 1);
    loadB(0);
    __syncthreads();               // As + B + idx[1] landed

    // ---- k-loop: 2 barriers, single buffer. idx[k] lives in slot k&1;
    // overwritten (by idxDMA(k+2)) only after its last read (stageA(k&1)
    // in iter k-1); within a phase stageA reads slot (k+1)&1 while idxDMA
    // writes slot k&1 — disjoint.
    #pragma unroll 1
    for (int k = 0; k < NOFF; ++k) {
        mfmaPhase();
        if (k + 1 < NOFF) {
            __syncthreads();                       // As reads done
            stageA((k + 1) & 1);                   // DMA gathers for k+1
            if (wid == 0 && k + 2 < NOFF) idxDMA(k + 2, k & 1);
            loadB(k + 1);
            __syncthreads();                       // vmcnt drain: all landed
        }
    }

    // ---- epilogue: store conv result + stats (direct atomics)
    float psum[2] = {0.f, 0.f};
    float psq[2]  = {0.f, 0.f};
    #pragma unroll
    for (int i = 0; i < 8; ++i) {
        #pragma unroll
        for (int r = 0; r < 4; ++r) {
            int grow = row0 + i * 16 + quad * 4 + r;
            if (grow < N_ACT) {
                #pragma unroll
                for (int j = 0; j < 2; ++j) {
                    float v = acc[i][j][r];
                    out[(size_t)grow * CH + wid * 32 + j * 16 + lr] = v;
                    psum[j] += v;
                    psq[j]  += v * v;
                }
            }
        }
    }
    #pragma unroll
    for (int j = 0; j < 2; ++j) {
        psum[j] += __shfl_xor(psum[j], 16, 64);
        psq[j]  += __shfl_xor(psq[j], 16, 64);
        psum[j] += __shfl_xor(psum[j], 32, 64);
        psq[j]  += __shfl_xor(psq[j], 32, 64);
    }
    if (quad == 0) {
        #pragma unroll
        for (int j = 0; j < 2; ++j) {
            int c = wid * 32 + j * 16 + lr;
            atomicAdd(&stats[c],      psum[j]);
            atomicAdd(&stats[CH + c], psq[j]);
        }
    }
}

// K3: fused finalize + bn_relu. Each thread derives scale/shift for its
// 4 channels from raw sums (stats L2-hot), then grid-strides the relu.
__global__ void bn_relu(const float* __restrict__ conv,
                        const float* __restrict__ stats,
                        const float* __restrict__ gamma,
                        const float* __restrict__ beta,
                        float* __restrict__ out) {
    const long long total = (long long)N_ACT * CH / 4;   // 6.4M groups
    long long tid = (long long)blockIdx.x * blockDim.x + threadIdx.x;
    // stride is a multiple of 32 -> (i & 31) invariant across iterations
    int c4 = (int)(tid & 31) * 4;
    float sc[4], sh[4];
    const float inv_n = 1.0f / (float)N_ACT;
    #pragma unroll
    for (int j = 0; j < 4; ++j) {
        int c = c4 + j;
        float mean = stats[c] * inv_n;
        float var  = stats[CH + c] * inv_n - mean * mean;
        float s    = gamma[c] * rsqrtf(var + 1e-4f);
        sc[j] = s;
        sh[j] = beta[c] - mean * s;
    }
    long long stride = (long long)gridDim.x * blockDim.x;
    for (long long i = tid; i < total; i += stride) {
        float4 v = ((const float4*)conv)[i];
        float4 o;
        o.x = fmaxf(v.x * sc[0] + sh[0], 0.f);
        o.y = fmaxf(v.y * sc[1] + sh[1], 0.f);
        o.z = fmaxf(v.z * sc[2] + sh[2], 0.f);
        o.w = fmaxf(v.w * sc[3] + sh[3], 0.f);
        ((float4*)out)[i] = o;
    }
}

extern "C" void kernel_launch(void* const* d_in, const int* in_sizes, int n_in,
                              void* d_out, int out_size, void* d_ws, size_t ws_size,
                              hipStream_t stream) {
    const float* features = (const float*)d_in[0];
    const int*   nbr      = (const int*)d_in[1];
    const float* W        = (const float*)d_in[2];
    const float* gamma    = (const float*)d_in[3];
    const float* beta     = (const float*)d_in[4];
    float* outp = (float*)d_out;

    char* ws = (char*)d_ws;
    // layout: feat_bf16 (51,200,000 B) | Wtp (884,736 B) | conv fp32
    // (102,400,000 B) | stats (512 floats) | zero page (256 B)
    unsigned short* feat_bf = (unsigned short*)ws;
    unsigned short* Wtp     = (unsigned short*)(ws + 51200000);
    float* conv             = (float*)(ws + 51200000 + 884736);
    float* stats            = (float*)(ws + 51200000 + 884736 + 102400000);
    float* zpage            = stats + 4 * CH;

    prep_and_cast<<<NOFF + 4096, 256, 0, stream>>>(
        features, W, feat_bf, Wtp, stats, zpage);
    conv_mfma<<<(N_ACT + TM - 1) / TM, 256, 0, stream>>>(
        feat_bf, nbr, Wtp, (const unsigned short*)zpage, conv, stats);
    bn_relu<<<4096, 256, 0, stream>>>(conv, stats, gamma, beta, outp);
}